// Round 1
// baseline (453.526 us; speedup 1.0000x reference)
//
#include <hip/hip_runtime.h>

// StructuredLayer: out[n][o] = sum_j x[n][(81*o + j) % 4096] * Weff[o][(81*o+j)%4096] + bias[o]
// Weff = weight*mask*gauge, cpn = 81 contiguous (mod 4096) columns per output.
//
// Chain trick: 81 * 2225 == 1 (mod 4096). In chain order o(k) = 2225*k mod 4096,
// the window start is exactly k, so windows slide +1 column per chain step.
// Wave layout: 8 tokens x 8 staggered chain positions (p = k mod 8) -> all 8 p-lanes
// read the SAME 8-column-aligned x chunk (LDS broadcast). Weight rows are re-laid-out
// as w3[k][jp], jp in [0,96), nonzero only for jp in [p, p+81): x column = (k & ~7) + jp.
// Results buffered in LDS by k; flush un-permutes via k = 81*o mod 4096 (coalesced writes).

typedef _Float16 h2 __attribute__((ext_vector_type(2)));
typedef _Float16 h4 __attribute__((ext_vector_type(4)));
typedef _Float16 h8 __attribute__((ext_vector_type(8)));

#define SH(v, i) __builtin_shufflevector(v, v, 2*(i), 2*(i)+1)

__device__ __forceinline__ float dot2f(h2 a, h2 b, float c) {
  float d;
  asm("v_dot2_f32_f16 %0, %1, %2, %3"
      : "=v"(d)
      : "v"(__builtin_bit_cast(unsigned int, a)),
        "v"(__builtin_bit_cast(unsigned int, b)),
        "v"(c));
  return d;
}

// ---------------- Pass 0: compact weights into w3[h][k][48] (fp16) ----------------
// Linear layout: idx = (h*4096 + k)*48 + jj, jp = h*48 + jj.
// w3 value = Weff[o(k)][(k&~7)+jp] for jp in [p, p+81), else 0.  (p = k & 7)
__global__ void __launch_bounds__(256) build_w3_kernel(
    const float* __restrict__ weight, const float* __restrict__ mask,
    const float* __restrict__ gauge, _Float16* __restrict__ w3) {
  int idx = blockIdx.x * 256 + threadIdx.x;   // grid covers exactly 2*4096*48
  int jj = idx % 48;
  int kk = (idx / 48) & 4095;
  int hh = idx / (48 * 4096);
  int jp = hh * 48 + jj;
  int pp = kk & 7;
  float v = 0.f;
  if (jp >= pp && jp < pp + 81) {
    int o   = (2225 * kk) & 4095;
    int col = ((kk & ~7) + jp) & 4095;
    size_t off = (size_t)o * 4096 + col;
    v = weight[off] * mask[off] * gauge[off];
  }
  w3[idx] = (_Float16)v;
}

// ---------------- Main kernel ----------------
// block: 1024 threads (16 waves), 8 tokens. LDS: x rows fp16 + out buffer fp16 + w3 dbuf.
__device__ __forceinline__ void do_half6(const _Float16* __restrict__ xrow,
                                         const _Float16* __restrict__ wrow,
                                         int colbase, float& a0, float& a1) {
  if (colbase <= 4048) {              // all 6 chunks in-bounds: immediate-offset reads
    const _Float16* xp = xrow + colbase;
#pragma unroll
    for (int jc = 0; jc < 6; ++jc) {
      h8 xv = *(const h8*)(xp + jc * 8);
      h8 wq = *(const h8*)(wrow + jc * 8);
      a0 = dot2f(SH(xv, 0), SH(wq, 0), a0);
      a1 = dot2f(SH(xv, 1), SH(wq, 1), a1);
      a0 = dot2f(SH(xv, 2), SH(wq, 2), a0);
      a1 = dot2f(SH(xv, 3), SH(wq, 3), a1);
    }
  } else {                            // wrap-around (rare: last few octets)
#pragma unroll
    for (int jc = 0; jc < 6; ++jc) {
      int cc = (colbase + jc * 8) & 4095;   // 8-aligned, never splits a 16B read
      h8 xv = *(const h8*)(xrow + cc);
      h8 wq = *(const h8*)(wrow + jc * 8);
      a0 = dot2f(SH(xv, 0), SH(wq, 0), a0);
      a1 = dot2f(SH(xv, 1), SH(wq, 1), a1);
      a0 = dot2f(SH(xv, 2), SH(wq, 2), a0);
      a1 = dot2f(SH(xv, 3), SH(wq, 3), a1);
    }
  }
}

__global__ void __launch_bounds__(1024) spmm_chain_kernel(
    const float* __restrict__ x, const _Float16* __restrict__ w3,
    const float* __restrict__ bias, float* __restrict__ out) {
  // Row stride 4104 halfs = 8208B = 2052 dwords == 4 (mod 32) banks:
  // 8 token rows spread across all 32 banks -> conflict-free b128 reads.
  __shared__ __align__(16) _Float16 xl[8 * 4104];   // 65,664 B
  __shared__ __align__(16) _Float16 ob[8 * 4104];   // 65,664 B
  __shared__ __align__(16) _Float16 wl[2 * 6144];   // 24,576 B (2 bufs x 128 rows x 48)

  const int tid = threadIdx.x;
  const size_t t0 = (size_t)blockIdx.x * 8;

  // ---- stage x: 8 rows f32 -> fp16 LDS (each row read exactly once chip-wide)
  const float4* xg = (const float4*)(x + t0 * 4096);
#pragma unroll
  for (int i = 0; i < 8; ++i) {
    float4 v = xg[i * 1024 + tid];
    h4 hv = {(_Float16)v.x, (_Float16)v.y, (_Float16)v.z, (_Float16)v.w};
    *(h4*)&xl[i * 4104 + tid * 4] = hv;
  }

  // ---- w3 staging prologue (half-chunk c=0,h=0): 128 rows x 96B = 768 x 16B
  const uint4* wsrc = (const uint4*)w3;
  uint4 wv;
  if (tid < 768) wv = wsrc[tid];

  const int g = tid >> 6, lane = tid & 63, t = lane >> 3, p = lane & 7;
  const _Float16* xrow = xl + t * 4104;
  float acc0, acc1;

#pragma unroll 1
  for (int c = 0; c < 32; ++c) {
    const int Kc = c * 128 + 8 * g;            // octet base = x column base (8-aligned)
    // ======== half h=0 (buf 0) ========
    if (tid < 768) *(uint4*)&wl[tid * 8] = wv;
    __syncthreads();
    if (tid < 768) wv = wsrc[(4096 + c * 128) * 6 + tid];   // prefetch (c, h=1)
    acc0 = 0.f; acc1 = 0.f;
    do_half6(xrow, wl + (8 * g + p) * 48, Kc, acc0, acc1);

    // ======== half h=1 (buf 1) ========
    if (tid < 768) *(uint4*)&wl[6144 + tid * 8] = wv;
    __syncthreads();
    if (tid < 768 && c + 1 < 32) wv = wsrc[(c + 1) * 768 + tid];  // prefetch (c+1, h=0)
    do_half6(xrow, wl + 6144 + (8 * g + p) * 48, Kc + 48, acc0, acc1);

    ob[t * 4104 + Kc + p] = (_Float16)(acc0 + acc1);   // result at chain index k
  }

  __syncthreads();
  // ---- flush: un-permute k = 81*o mod 4096, add bias, coalesced f32 writes
  float* og = out + t0 * 4096;
#pragma unroll 4
  for (int i = 0; i < 32; ++i) {
    int e = i * 1024 + tid;
    int tt = e >> 12, o = e & 4095;
    int k = (81 * o) & 4095;
    og[(size_t)tt * 4096 + o] = (float)ob[tt * 4104 + k] + bias[o];
  }
}

extern "C" void kernel_launch(void* const* d_in, const int* in_sizes, int n_in,
                              void* d_out, int out_size, void* d_ws, size_t ws_size,
                              hipStream_t stream) {
  const float* x      = (const float*)d_in[0];
  const float* weight = (const float*)d_in[1];
  const float* bias   = (const float*)d_in[2];
  const float* mask   = (const float*)d_in[3];
  const float* gauge  = (const float*)d_in[4];
  float* out = (float*)d_out;
  _Float16* w3 = (_Float16*)d_ws;   // needs 2*4096*48*2 = 786,432 B of workspace

  build_w3_kernel<<<1536, 256, 0, stream>>>(weight, mask, gauge, w3);
  spmm_chain_kernel<<<1024, 1024, 0, stream>>>(x, w3, bias, out);
}

// Round 2
// 357.952 us; speedup vs baseline: 1.2670x; 1.2670x over previous
//
#include <hip/hip_runtime.h>

// StructuredLayer via chain-ordered dense micro-GEMMs.
// Chain trick: 81*2225 == 1 (mod 4096); in chain order o(k)=2225k mod 4096 the
// 81-wide window of output o(k) starts exactly at column k. For a 16-k tile
// (k = K16+n, n<16) every window lies in columns [K16, K16+96):
//   out_chain[t][K16+n] = sum_{kk<96} x[t][(K16+kk)%4096] * w4[K16/16][n][kk]
// -> dense 16x16x96 GEMM = 3x mfma_f32_16x16x32_f16. Results land in an LDS
// buffer indexed by k; flush un-permutes via k = 81*o mod 4096 (coalesced).

typedef _Float16 h4 __attribute__((ext_vector_type(4)));
typedef _Float16 h8 __attribute__((ext_vector_type(8)));
typedef float f32x4 __attribute__((ext_vector_type(4)));

// ---------------- Pass 0: pack weights into w4[256][16][96] fp16 ----------------
// w4[m][n][kk] = Weff[o(m*16+n)][(m*16+kk)%4096] if kk in [n, n+81) else 0.
__global__ void __launch_bounds__(256) build_w4_kernel(
    const float* __restrict__ weight, const float* __restrict__ mask,
    const float* __restrict__ gauge, _Float16* __restrict__ w4) {
  int idx = blockIdx.x * 256 + threadIdx.x;   // grid covers 256*16*96 = 393216
  int kk = idx % 96;
  int n  = (idx / 96) & 15;
  int m  = idx / 1536;
  int k  = m * 16 + n;
  float v = 0.f;
  if (kk >= n && kk < n + 81) {
    int o   = (2225 * k) & 4095;
    int col = (m * 16 + kk) & 4095;
    size_t off = (size_t)o * 4096 + col;
    v = weight[off] * mask[off] * gauge[off];
  }
  w4[idx] = (_Float16)v;
}

// ---------------- Main kernel: 8 tokens/block, 16 waves, 256 k-tiles ----------------
__global__ void __launch_bounds__(1024, 4) spmm_mfma_kernel(
    const float* __restrict__ x, const _Float16* __restrict__ w4,
    const float* __restrict__ bias, float* __restrict__ out) {
  // Row stride 4104 halfs (8208B = 2052 dw == 4 mod 32): A-frag reads are
  // conflict-free per 16-lane phase (8 rows x 4dw span exactly 32 banks).
  __shared__ __align__(16) _Float16 xl[8 * 4104];   // 65,664 B
  __shared__ __align__(16) _Float16 ob[8 * 4104];   // 65,664 B

  const int tid = threadIdx.x;
  const size_t t0 = (size_t)blockIdx.x * 8;

  // ---- stage x: 8 token rows f32 -> fp16 LDS (each row read once chip-wide)
  const float4* xg = (const float4*)(x + t0 * 4096);
#pragma unroll
  for (int i = 0; i < 8; ++i) {
    float4 v = xg[i * 1024 + tid];
    h4 hv = {(_Float16)v.x, (_Float16)v.y, (_Float16)v.z, (_Float16)v.w};
    *(h4*)&xl[i * 4104 + tid * 4] = hv;
  }
  __syncthreads();

  const int w = tid >> 6, lane = tid & 63;
  const int l15 = lane & 15, g = lane >> 4;     // A/B k-group 0..3
  const int tA = l15 & 7;                       // token row (rows 8..15 duplicate)
  const _Float16* xrow = xl + tA * 4104;
  const int aoff = 8 * g;                       // + 16m + 32s, &4095
  // B fragment global address (half idx): (16m + l15)*96 + 32s + 8g
  const _Float16* bbase = w4 + (size_t)l15 * 96 + 8 * g;

  int m = w * 16;                               // this wave's 16 tiles
  const _Float16* bp = bbase + (size_t)m * 1536;
  h8 b0 = *(const h8*)(bp);
  h8 b1 = *(const h8*)(bp + 32);
  h8 b2 = *(const h8*)(bp + 64);

#pragma unroll 2
  for (int i = 0; i < 16; ++i, ++m) {
    const int K16 = m << 4;
    const int o0 = (K16 + aoff) & 4095;
    const int o1 = (K16 + 32 + aoff) & 4095;
    const int o2 = (K16 + 64 + aoff) & 4095;
    h8 a0 = *(const h8*)(xrow + o0);
    h8 a1 = *(const h8*)(xrow + o1);
    h8 a2 = *(const h8*)(xrow + o2);
    h8 nb0, nb1, nb2;                           // prefetch next tile's B
    if (i < 15) {
      const _Float16* np = bbase + (size_t)(m + 1) * 1536;
      nb0 = *(const h8*)(np);
      nb1 = *(const h8*)(np + 32);
      nb2 = *(const h8*)(np + 64);
    } else { nb0 = b0; nb1 = b1; nb2 = b2; }
    f32x4 acc = {0.f, 0.f, 0.f, 0.f};
    acc = __builtin_amdgcn_mfma_f32_16x16x32_f16(a0, b0, acc, 0, 0, 0);
    acc = __builtin_amdgcn_mfma_f32_16x16x32_f16(a1, b1, acc, 0, 0, 0);
    acc = __builtin_amdgcn_mfma_f32_16x16x32_f16(a2, b2, acc, 0, 0, 0);
    // C layout: col = lane&15 (= n), row = 4*(lane>>4)+reg (= token, rows 8..15 dup)
    if (lane < 32) {
      _Float16* op = ob + (g * 4) * 4104 + K16 + l15;
#pragma unroll
      for (int r = 0; r < 4; ++r) op[r * 4104] = (_Float16)acc[r];
    }
    b0 = nb0; b1 = nb1; b2 = nb2;
  }
  __syncthreads();

  // ---- flush: un-permute k = 81*o mod 4096, add bias, coalesced f32 writes
  float* og = out + t0 * 4096;
#pragma unroll
  for (int it = 0; it < 32; ++it) {
    int e = it * 1024 + tid;
    int tt = e >> 12, o = e & 4095;
    int k = (81 * o) & 4095;
    og[(size_t)tt * 4096 + o] = (float)ob[tt * 4104 + k] + bias[o];
  }
}

extern "C" void kernel_launch(void* const* d_in, const int* in_sizes, int n_in,
                              void* d_out, int out_size, void* d_ws, size_t ws_size,
                              hipStream_t stream) {
  const float* x      = (const float*)d_in[0];
  const float* weight = (const float*)d_in[1];
  const float* bias   = (const float*)d_in[2];
  const float* mask   = (const float*)d_in[3];
  const float* gauge  = (const float*)d_in[4];
  float* out = (float*)d_out;
  _Float16* w4 = (_Float16*)d_ws;   // 256*16*96*2 = 786,432 B of workspace

  build_w4_kernel<<<1536, 256, 0, stream>>>(weight, mask, gauge, w4);
  spmm_mfma_kernel<<<1024, 1024, 0, stream>>>(x, w4, bias, out);
}